// Round 8
// baseline (224.507 us; speedup 1.0000x reference)
//
#include <hip/hip_runtime.h>

namespace {
constexpr int kB  = 8192;  // batch
constexpr int kD  = 768;   // emb dim
constexpr int kM  = 96;    // subvectors
constexpr int kK  = 256;   // codes
constexpr int kDS = 8;     // dsub
constexpr int kThreads = 128;           // 2 waves
constexpr int kBPT = 4;                 // b rows per thread
constexpr int kBT  = kThreads * kBPT;   // 512 b per block
// Screen margin in s-units (s = v.c - c2/2). Worst-case ordering slack
// between s-ordering (fma chain) and numpy's exact p-ordering
// (seq mul-add, (2vc - v2) - c2 with per-step rounding) <= ~2.2e-5.
constexpr float kEPS = 1e-4f;
}

// numpy pairwise sum for n=8: ((q0+q1)+(q2+q3)) + ((q4+q5)+(q6+q7))
__device__ __forceinline__ float tree8_sq(float4 a, float4 b) {
    float q0 = __fmul_rn(a.x, a.x), q1 = __fmul_rn(a.y, a.y);
    float q2 = __fmul_rn(a.z, a.z), q3 = __fmul_rn(a.w, a.w);
    float q4 = __fmul_rn(b.x, b.x), q5 = __fmul_rn(b.y, b.y);
    float q6 = __fmul_rn(b.z, b.z), q7 = __fmul_rn(b.w, b.w);
    return __fadd_rn(__fadd_rn(__fadd_rn(q0, q1), __fadd_rn(q2, q3)),
                     __fadd_rn(__fadd_rn(q4, q5), __fadd_rn(q6, q7)));
}

__device__ __forceinline__ float tree8_sq8(const float* v) {
    float q0 = __fmul_rn(v[0], v[0]), q1 = __fmul_rn(v[1], v[1]);
    float q2 = __fmul_rn(v[2], v[2]), q3 = __fmul_rn(v[3], v[3]);
    float q4 = __fmul_rn(v[4], v[4]), q5 = __fmul_rn(v[5], v[5]);
    float q6 = __fmul_rn(v[6], v[6]), q7 = __fmul_rn(v[7], v[7]);
    return __fadd_rn(__fadd_rn(__fadd_rn(q0, q1), __fadd_rn(q2, q3)),
                     __fadd_rn(__fadd_rn(q4, q5), __fadd_rn(q6, q7)));
}

__global__ __launch_bounds__(kThreads, 4)
void pq_screen_kernel(const float* __restrict__ vecs,
                      const float* __restrict__ cbg,
                      float* __restrict__ out) {
    // numpy does mul then add with separate roundings — forbid implicit FMA.
    // (The screen uses EXPLICIT __builtin_fmaf; exact path stays mul+add.)
    #pragma clang fp contract(off)

    __shared__ float4 s_cb[kK][2];   // raw f32 code rows
    __shared__ float  s_nc2h[kK];    // -c2/2 (exact: *0.5 and negate are exact)

    const int tid = threadIdx.x;
    const int m   = blockIdx.x % kM;
    const int bt  = blockIdx.x / kM;
    const float* __restrict__ cbm = cbg + (size_t)m * (kK * kDS);

    // ---- stage codebook slice (coalesced 32B per thread per row)
    for (int r = tid; r < kK; r += kThreads) {
        const float4* cr = reinterpret_cast<const float4*>(cbm + r * kDS);
        float4 a = cr[0], b = cr[1];
        s_cb[r][0] = a; s_cb[r][1] = b;
        s_nc2h[r] = -0.5f * tree8_sq(a, b);
    }
    __syncthreads();

    // ---- load kBPT v-rows (raw; exact path derives everything from these)
    const size_t b0 = (size_t)bt * kBT + tid;
    float v[kBPT][kDS];
#pragma unroll
    for (int j = 0; j < kBPT; ++j) {
        const float* vr = vecs + (b0 + (size_t)j * kThreads) * kD + m * kDS;
        float4 a = reinterpret_cast<const float4*>(vr)[0];
        float4 c = reinterpret_cast<const float4*>(vr)[1];
        v[j][0] = a.x; v[j][1] = a.y; v[j][2] = a.z; v[j][3] = a.w;
        v[j][4] = c.x; v[j][5] = c.y; v[j][6] = c.z; v[j][7] = c.w;
    }

    float best[kBPT], b2[kBPT];
    int   bidx[kBPT];
#pragma unroll
    for (int j = 0; j < kBPT; ++j) {
        best[j] = -3.402823466e38f; b2[j] = -3.402823466e38f; bidx[j] = 0;
    }

    // ---- fast screen: s_k = fma(v, c_k, -c2_k/2); track top-2 + argidx.
#pragma unroll 2
    for (int k = 0; k < kK; ++k) {
        const float4 ca  = s_cb[k][0];
        const float4 cb4 = s_cb[k][1];
        const float  nb  = s_nc2h[k];
#pragma unroll
        for (int j = 0; j < kBPT; ++j) {
            float s = __builtin_fmaf(v[j][0], ca.x, nb);
            s = __builtin_fmaf(v[j][1], ca.y, s);
            s = __builtin_fmaf(v[j][2], ca.z, s);
            s = __builtin_fmaf(v[j][3], ca.w, s);
            s = __builtin_fmaf(v[j][4], cb4.x, s);
            s = __builtin_fmaf(v[j][5], cb4.y, s);
            s = __builtin_fmaf(v[j][6], cb4.z, s);
            s = __builtin_fmaf(v[j][7], cb4.w, s);
            bool gt = s > best[j];
            b2[j]   = fmaxf(b2[j], fminf(s, best[j]));
            best[j] = fmaxf(s, best[j]);
            bidx[j] = gt ? k : bidx[j];
        }
    }

    // ---- resolve + write
#pragma unroll
    for (int j = 0; j < kBPT; ++j) {
        int win = bidx[j];
        if (!(best[j] - b2[j] > kEPS)) {
            // slow path (rare): exact bitwise-numpy p for candidates
            const float thr = best[j] - kEPS;
            const float v2  = tree8_sq8(v[j]);
            float bp = -3.402823466e38f;
            int   bk = 0;
            for (int k = 0; k < kK; ++k) {
                const float4 ca  = s_cb[k][0];
                const float4 cb4 = s_cb[k][1];
                const float  nb  = s_nc2h[k];
                // identical op order to the fast screen => identical bits
                float s = __builtin_fmaf(v[j][0], ca.x, nb);
                s = __builtin_fmaf(v[j][1], ca.y, s);
                s = __builtin_fmaf(v[j][2], ca.z, s);
                s = __builtin_fmaf(v[j][3], ca.w, s);
                s = __builtin_fmaf(v[j][4], cb4.x, s);
                s = __builtin_fmaf(v[j][5], cb4.y, s);
                s = __builtin_fmaf(v[j][6], cb4.z, s);
                s = __builtin_fmaf(v[j][7], cb4.w, s);
                if (s >= thr) {
                    // exact numpy: seq mul-then-add, (2vc - v2) - c2
                    float acc = __fmul_rn(v[j][0], ca.x);
                    acc = __fadd_rn(acc, __fmul_rn(v[j][1], ca.y));
                    acc = __fadd_rn(acc, __fmul_rn(v[j][2], ca.z));
                    acc = __fadd_rn(acc, __fmul_rn(v[j][3], ca.w));
                    acc = __fadd_rn(acc, __fmul_rn(v[j][4], cb4.x));
                    acc = __fadd_rn(acc, __fmul_rn(v[j][5], cb4.y));
                    acc = __fadd_rn(acc, __fmul_rn(v[j][6], cb4.z));
                    acc = __fadd_rn(acc, __fmul_rn(v[j][7], cb4.w));
                    const float c2 = -2.0f * nb;   // bitwise == original c2
                    float p = __fsub_rn(__fsub_rn(__fmul_rn(2.0f, acc), v2), c2);
                    // strict '>' ascending k == np.argmax first-index wins
                    if (p > bp) { bp = p; bk = k; }
                }
            }
            win = bk;
        }
        // output: exact copy of winning code row (bitwise == reference)
        float4 q0 = s_cb[win][0], q1 = s_cb[win][1];
        float4* op = reinterpret_cast<float4*>(
            out + (b0 + (size_t)j * kThreads) * kD + m * kDS);
        op[0] = q0;
        op[1] = q1;
    }
}

extern "C" void kernel_launch(void* const* d_in, const int* in_sizes, int n_in,
                              void* d_out, int out_size, void* d_ws, size_t ws_size,
                              hipStream_t stream) {
    const float* vecs = (const float*)d_in[0];   // (8192, 768) f32
    const float* cbg  = (const float*)d_in[1];   // (96, 256, 8) f32
    float* out = (float*)d_out;                  // (8192, 768) f32

    dim3 grid(kM * (kB / kBT));                  // 96 * 16 = 1536 blocks
    pq_screen_kernel<<<grid, kThreads, 0, stream>>>(vecs, cbg, out);
}

// Round 9
// 205.121 us; speedup vs baseline: 1.0945x; 1.0945x over previous
//
#include <hip/hip_runtime.h>

namespace {
constexpr int kB  = 8192;  // batch
constexpr int kD  = 768;   // emb dim
constexpr int kM  = 96;    // subvectors
constexpr int kK  = 256;   // codes
constexpr int kDS = 8;     // dsub
constexpr int kThreads = 256;           // 4 waves (R3-proven shape)
constexpr int kBPT = 4;                 // b rows per thread
constexpr int kBT  = kThreads * kBPT;   // 1024 b per block
// Screen margin in s-units (s = fma-chain(v.c, -c2/2)). Ordering slack vs
// numpy's exact p = (2vc_seq - v2) - c2 is <= ~5e-6; EPS gives 20x margin.
// Any exact tie has s-gap ~0 -> always flagged -> resolved exactly.
constexpr float kEPS = 1e-4f;
}

// numpy pairwise sum for n=8: ((q0+q1)+(q2+q3)) + ((q4+q5)+(q6+q7))
__device__ __forceinline__ float tree8_sq(float4 a, float4 b) {
    float q0 = __fmul_rn(a.x, a.x), q1 = __fmul_rn(a.y, a.y);
    float q2 = __fmul_rn(a.z, a.z), q3 = __fmul_rn(a.w, a.w);
    float q4 = __fmul_rn(b.x, b.x), q5 = __fmul_rn(b.y, b.y);
    float q6 = __fmul_rn(b.z, b.z), q7 = __fmul_rn(b.w, b.w);
    return __fadd_rn(__fadd_rn(__fadd_rn(q0, q1), __fadd_rn(q2, q3)),
                     __fadd_rn(__fadd_rn(q4, q5), __fadd_rn(q6, q7)));
}

__global__ __launch_bounds__(kThreads)
void pq_screen_kernel(const float* __restrict__ vecs,
                      const float* __restrict__ cbg,
                      float* __restrict__ out,
                      unsigned* __restrict__ qcnt,   // ws[0]
                      unsigned* __restrict__ queue,  // ws + 64B
                      unsigned qcap) {
    #pragma clang fp contract(off)

    __shared__ float4 s_cb[kK][2];   // raw f32 code rows (bitwise copies)
    __shared__ float  s_seed[kK];    // -c2/2 (exact scale of exact c2)

    const int tid = threadIdx.x;
    const int m   = blockIdx.x % kM;
    const int bt  = blockIdx.x / kM;

    // stage codebook slice: thread t = code row t (coalesced 32B chunks)
    {
        const float4* src = reinterpret_cast<const float4*>(cbg) + (size_t)m * (kK * kDS / 4);
        float4 a = src[2 * tid + 0];
        float4 b = src[2 * tid + 1];
        s_cb[tid][0] = a; s_cb[tid][1] = b;
        s_seed[tid] = -0.5f * tree8_sq(a, b);
    }
    __syncthreads();

    const size_t b0 = (size_t)bt * kBT + tid;
    float v[kBPT][kDS];
#pragma unroll
    for (int j = 0; j < kBPT; ++j) {
        const float* vr = vecs + (b0 + (size_t)j * kThreads) * kD + m * kDS;
        float4 a = reinterpret_cast<const float4*>(vr)[0];
        float4 c = reinterpret_cast<const float4*>(vr)[1];
        v[j][0] = a.x; v[j][1] = a.y; v[j][2] = a.z; v[j][3] = a.w;
        v[j][4] = c.x; v[j][5] = c.y; v[j][6] = c.z; v[j][7] = c.w;
    }

    float best[kBPT], b2[kBPT];
    int   bidx[kBPT];
#pragma unroll
    for (int j = 0; j < kBPT; ++j) {
        best[j] = -3.402823466e38f; b2[j] = -3.402823466e38f; bidx[j] = 0;
    }

    // pure screen loop: 8 fma + 5 tracking ops per cell, nothing else.
#pragma unroll 2
    for (int k = 0; k < kK; ++k) {
        const float4 ca  = s_cb[k][0];
        const float4 cb4 = s_cb[k][1];
        const float  sd  = s_seed[k];
#pragma unroll
        for (int j = 0; j < kBPT; ++j) {
            float s = __builtin_fmaf(v[j][0], ca.x, sd);
            s = __builtin_fmaf(v[j][1], ca.y, s);
            s = __builtin_fmaf(v[j][2], ca.z, s);
            s = __builtin_fmaf(v[j][3], ca.w, s);
            s = __builtin_fmaf(v[j][4], cb4.x, s);
            s = __builtin_fmaf(v[j][5], cb4.y, s);
            s = __builtin_fmaf(v[j][6], cb4.z, s);
            s = __builtin_fmaf(v[j][7], cb4.w, s);
            float mn = fminf(s, best[j]);          // v_min
            b2[j]    = fmaxf(b2[j], mn);           // v_max
            bool gt  = s > best[j];                // v_cmp
            best[j]  = fmaxf(s, best[j]);          // v_max
            bidx[j]  = gt ? k : bidx[j];           // v_cndmask
        }
    }

    // epilogue: write screen winner; enqueue near-ties for exact resolve.
#pragma unroll
    for (int j = 0; j < kBPT; ++j) {
        const int win = bidx[j];
        float4 q0 = s_cb[win][0], q1 = s_cb[win][1];
        const size_t brow = b0 + (size_t)j * kThreads;
        float4* op = reinterpret_cast<float4*>(out + brow * kD + m * kDS);
        op[0] = q0;
        op[1] = q1;
        if (!(best[j] - b2[j] > kEPS)) {
            unsigned pos = atomicAdd(qcnt, 1u);
            if (pos < qcap) queue[pos] = (unsigned)(brow * kM + m);
        }
    }
}

// Exact resolver for flagged cells: full bitwise-numpy argmax (R3-proven).
__global__ __launch_bounds__(256)
void pq_resolve_kernel(const float* __restrict__ vecs,
                       const float* __restrict__ cbg,
                       float* __restrict__ out,
                       const unsigned* __restrict__ qcnt,
                       const unsigned* __restrict__ queue,
                       unsigned qcap) {
    #pragma clang fp contract(off)
    const unsigned n = min(*qcnt, qcap);
    for (unsigned i = blockIdx.x * blockDim.x + threadIdx.x; i < n;
         i += gridDim.x * blockDim.x) {
        const unsigned cell = queue[i];
        const unsigned b = cell / kM;
        const unsigned m = cell % kM;
        const float* vr = vecs + (size_t)b * kD + m * kDS;
        float v0 = vr[0], v1 = vr[1], v2e = vr[2], v3 = vr[3];
        float v4 = vr[4], v5 = vr[5], v6 = vr[6], v7 = vr[7];
        // v2 = np tree8 of squares
        float q0 = __fmul_rn(v0, v0), q1 = __fmul_rn(v1, v1);
        float q2 = __fmul_rn(v2e, v2e), q3 = __fmul_rn(v3, v3);
        float q4 = __fmul_rn(v4, v4), q5 = __fmul_rn(v5, v5);
        float q6 = __fmul_rn(v6, v6), q7 = __fmul_rn(v7, v7);
        float vsq = __fadd_rn(__fadd_rn(__fadd_rn(q0, q1), __fadd_rn(q2, q3)),
                              __fadd_rn(__fadd_rn(q4, q5), __fadd_rn(q6, q7)));
        const float* cbm = cbg + (size_t)m * (kK * kDS);
        float bp = -3.402823466e38f;
        int   bk = 0;
        for (int k = 0; k < kK; ++k) {
            const float4* cr = reinterpret_cast<const float4*>(cbm + k * kDS);
            float4 ca = cr[0], cb4 = cr[1];
            float c0 = __fmul_rn(ca.x, ca.x),  c1 = __fmul_rn(ca.y, ca.y);
            float c2q = __fmul_rn(ca.z, ca.z), c3 = __fmul_rn(ca.w, ca.w);
            float c4 = __fmul_rn(cb4.x, cb4.x), c5 = __fmul_rn(cb4.y, cb4.y);
            float c6 = __fmul_rn(cb4.z, cb4.z), c7 = __fmul_rn(cb4.w, cb4.w);
            float csq = __fadd_rn(__fadd_rn(__fadd_rn(c0, c1), __fadd_rn(c2q, c3)),
                                  __fadd_rn(__fadd_rn(c4, c5), __fadd_rn(c6, c7)));
            float acc = __fmul_rn(v0, ca.x);
            acc = __fadd_rn(acc, __fmul_rn(v1, ca.y));
            acc = __fadd_rn(acc, __fmul_rn(v2e, ca.z));
            acc = __fadd_rn(acc, __fmul_rn(v3, ca.w));
            acc = __fadd_rn(acc, __fmul_rn(v4, cb4.x));
            acc = __fadd_rn(acc, __fmul_rn(v5, cb4.y));
            acc = __fadd_rn(acc, __fmul_rn(v6, cb4.z));
            acc = __fadd_rn(acc, __fmul_rn(v7, cb4.w));
            float p = __fsub_rn(__fsub_rn(__fmul_rn(2.0f, acc), vsq), csq);
            if (p > bp) { bp = p; bk = k; }   // strict '>' asc k == np.argmax
        }
        const float4* wr = reinterpret_cast<const float4*>(cbm + bk * kDS);
        float4 w0 = wr[0], w1 = wr[1];
        float4* op = reinterpret_cast<float4*>(out + (size_t)b * kD + m * kDS);
        op[0] = w0;
        op[1] = w1;
    }
}

extern "C" void kernel_launch(void* const* d_in, const int* in_sizes, int n_in,
                              void* d_out, int out_size, void* d_ws, size_t ws_size,
                              hipStream_t stream) {
    const float* vecs = (const float*)d_in[0];   // (8192, 768) f32
    const float* cbg  = (const float*)d_in[1];   // (96, 256, 8) f32
    float* out = (float*)d_out;                  // (8192, 768) f32

    unsigned* qcnt  = (unsigned*)d_ws;
    unsigned* queue = (unsigned*)((char*)d_ws + 64);
    unsigned  qcap  = (ws_size > 64)
                    ? (unsigned)min((ws_size - 64) / 4, (size_t)(kB * kM))
                    : 0u;

    hipMemsetAsync(qcnt, 0, sizeof(unsigned), stream);   // ws is re-poisoned

    dim3 grid(kM * (kB / kBT));                  // 96 * 8 = 768 blocks
    pq_screen_kernel<<<grid, kThreads, 0, stream>>>(vecs, cbg, out,
                                                    qcnt, queue, qcap);
    pq_resolve_kernel<<<128, 256, 0, stream>>>(vecs, cbg, out,
                                               qcnt, queue, qcap);
}